// Round 3
// baseline (495.765 us; speedup 1.0000x reference)
//
#include <hip/hip_runtime.h>
#include <math.h>

// Morphological opening, 10x10 flat kernel, SAME pad (window [i-4, i+5]).
// NHWC fp32 [16,512,512,8]. Two symmetric kernels:
//   erosion  (min): in -> ws
//   dilation (max): ws -> out   (reference pads the eroded map with -inf)
// Each kernel fuses its W-pass + H-pass through one small LDS tile:
//   phase 1: minW/maxW for 41 halo rows x 32 px, global->LDS, 17-tap run trick
//   phase 2: minH/maxH vertical run-of-8 from LDS, coalesced stores.
// LDS = 41 * 65 * 16 B = 42.6 KB -> 3 blocks/CU (vs R2's 147 KB -> 1/CU).

#define W_F4   1024              // 512 px * 2 f4 (8 ch)
#define IMG_F4 (512 * W_F4)
#define TH     32                // output rows per tile
#define TW     32                // output px per tile
#define ROWS   41                // TH + 9 halo rows of minW/maxW
#define S_M    65                // LDS row stride in f4 (64 + 1 pad, odd)

__device__ __forceinline__ float4 f4min(float4 a, float4 b) {
    return make_float4(fminf(a.x,b.x), fminf(a.y,b.y), fminf(a.z,b.z), fminf(a.w,b.w));
}
__device__ __forceinline__ float4 f4max(float4 a, float4 b) {
    return make_float4(fmaxf(a.x,b.x), fmaxf(a.y,b.y), fmaxf(a.z,b.z), fmaxf(a.w,b.w));
}
template <bool IS_MIN>
__device__ __forceinline__ float4 f4op(float4 a, float4 b) {
    return IS_MIN ? f4min(a, b) : f4max(a, b);
}

template <bool IS_MIN>
__global__ __launch_bounds__(256) void morph(const float4* __restrict__ in,
                                             float4* __restrict__ out) {
    __shared__ float4 sM[ROWS * S_M];    // 2665 f4 = 42,640 B

    const float  IDENT  = IS_MIN ? INFINITY : -INFINITY;
    const float4 ident4 = make_float4(IDENT, IDENT, IDENT, IDENT);

    const int t  = threadIdx.x;
    const int h0 = blockIdx.y * TH;
    const int w0 = blockIdx.x * TW;
    const int n  = blockIdx.z;

    const float4* img  = in  + (size_t)n * IMG_F4;
    float4*       oimg = out + (size_t)n * IMG_F4;

    // ---- phase 1: W-direction op, global -> sM ----
    // 328 tasks: (c4 in {0,1}) x (r in [0,41)) x (p in [0,4) run of 8 px).
    // Lane decode keeps c4 fastest then r: LDS write aliasing <= 2-way (free).
    for (int rho = t; rho < 2 * ROWS * (TW / 8); rho += 256) {
        int c4 = rho & 1;
        int rp = rho >> 1;
        int r  = rp % ROWS;
        int p  = rp / ROWS;
        int h  = h0 - 4 + r;
        bool hok = (h >= 0) && (h < 512);
        const float4* rowp = img + (size_t)(hok ? h : 0) * W_F4;

        float4 v[17];
#pragma unroll
        for (int q = 0; q < 17; q++) {
            int wpx = w0 + p * 8 - 4 + q;
            bool ok = hok && (wpx >= 0) && (wpx < 512);
            v[q] = ok ? rowp[(size_t)(wpx * 2 + c4)] : ident4;
        }
        float4 L[9]; L[8] = v[8];
#pragma unroll
        for (int i = 7; i >= 0; i--) L[i] = f4op<IS_MIN>(v[i], L[i + 1]);
        float4 rr = v[9];
#pragma unroll
        for (int i = 0; i < 8; i++) {
            if (i > 0) rr = f4op<IS_MIN>(rr, v[9 + i]);
            sM[r * S_M + (p * 8 + i) * 2 + c4] = f4op<IS_MIN>(L[i], rr);
        }
    }
    __syncthreads();

    // ---- phase 2: H-direction op, sM -> global (coalesced) ----
    // 256 tasks: c = f4 col (0..63), p = row-run (0..3). Output row h0+p*8+i
    // needs sM rows p*8+i .. p*8+i+9  ->  taps p*8+q, q in [0,17).
    {
        int c = t & 63;
        int p = t >> 6;
        float4 v[17];
#pragma unroll
        for (int q = 0; q < 17; q++)
            v[q] = sM[(p * 8 + q) * S_M + c];
        float4 L[9]; L[8] = v[8];
#pragma unroll
        for (int i = 7; i >= 0; i--) L[i] = f4op<IS_MIN>(v[i], L[i + 1]);
        float4 rr = v[9];
#pragma unroll
        for (int i = 0; i < 8; i++) {
            if (i > 0) rr = f4op<IS_MIN>(rr, v[9 + i]);
            oimg[(size_t)(h0 + p * 8 + i) * W_F4 + (w0 * 2 + c)] = f4op<IS_MIN>(L[i], rr);
        }
    }
}

extern "C" void kernel_launch(void* const* d_in, const int* in_sizes, int n_in,
                              void* d_out, int out_size, void* d_ws, size_t ws_size,
                              hipStream_t stream) {
    const float4* in  = (const float4*)d_in[0];
    float4*       out = (float4*)d_out;
    float4*       ws  = (float4*)d_ws;   // eroded intermediate, 128 MiB

    dim3 grid(512 / TW, 512 / TH, 16);   // 16 x 16 x 16 = 4096 blocks

    morph<true ><<<grid, 256, 0, stream>>>(in, ws);   // erosion
    morph<false><<<grid, 256, 0, stream>>>(ws, out);  // dilation
}

// Round 4
// 368.293 us; speedup vs baseline: 1.3461x; 1.3461x over previous
//
#include <hip/hip_runtime.h>
#include <math.h>

// Morphological opening, 10x10 flat kernel, SAME pad (window [i-4, i+5]).
// NHWC fp32 [16,512,512,8]. Two fused kernels:
//   erosion  (min): in -> ws      dilation (max): ws -> out (pads -inf)
// Per block (32x32 px output tile):
//   phase 1: H-direction op, GLOBAL->LDS. Coalesced: lanes = contiguous f4
//            cols, 20 row-taps -> van Herk run of 11 output rows.
//   phase 2: W-direction op, LDS->GLOBAL. 20 col-taps -> run of 11 px.
// __launch_bounds__(256,3): VGPR cap ~170 so all 20 float4 taps stay in
// flight (R1/R3 got 40/68 VGPRs -> serialized memory latency).

#define W_F4   1024              // 512 px * 2 f4 (8 ch)
#define IMG_F4 (512 * W_F4)
#define TH     32
#define TW     32
#define MCOLS  82                // (TW + 9) px * 2 f4
#define S_M    83                // LDS row stride (odd)

__device__ __forceinline__ float4 f4min(float4 a, float4 b) {
    return make_float4(fminf(a.x,b.x), fminf(a.y,b.y), fminf(a.z,b.z), fminf(a.w,b.w));
}
__device__ __forceinline__ float4 f4max(float4 a, float4 b) {
    return make_float4(fmaxf(a.x,b.x), fmaxf(a.y,b.y), fmaxf(a.z,b.z), fmaxf(a.w,b.w));
}
template <bool IS_MIN>
__device__ __forceinline__ float4 f4op(float4 a, float4 b) {
    return IS_MIN ? f4min(a, b) : f4max(a, b);
}

// van Herk on 20 taps -> 11 outputs (window 10): out[i] = op(v[i..i+9]).
// S[i] = op(v[i..9]) (suffix of first segment); P streams v[10..19].
// Emit(i, val) is a lambda-ish macro via functor F.
template <bool IS_MIN, typename EMIT>
__device__ __forceinline__ void run11(const float4 (&v)[20], EMIT emit) {
    float4 S[10];
    S[9] = v[9];
#pragma unroll
    for (int i = 8; i >= 0; i--) S[i] = f4op<IS_MIN>(v[i], S[i + 1]);
    emit(0, S[0]);
    float4 P = v[10];
#pragma unroll
    for (int i = 1; i <= 9; i++) {
        emit(i, f4op<IS_MIN>(S[i], P));
        if (i < 9) P = f4op<IS_MIN>(P, v[10 + i]);
    }
    P = f4op<IS_MIN>(P, v[19]);
    emit(10, P);
}

template <bool IS_MIN>
__global__ __launch_bounds__(256, 3) void morph(const float4* __restrict__ in,
                                                float4* __restrict__ out) {
    __shared__ float4 sM[TH * S_M];      // 32*83 f4 = 42,496 B -> 3 blocks/CU

    const float  IDENT  = IS_MIN ? INFINITY : -INFINITY;
    const float4 ident4 = make_float4(IDENT, IDENT, IDENT, IDENT);

    const int t  = threadIdx.x;
    const int h0 = blockIdx.y * TH;
    const int w0 = blockIdx.x * TW;

    const float4* img  = in  + (size_t)blockIdx.z * IMG_F4;
    float4*       oimg = out + (size_t)blockIdx.z * IMG_F4;

    // ---- phase 1: H-op, global -> sM.  246 tasks: c in [0,82), p in [0,3) ----
    if (t < 246) {
        const int c = t % MCOLS;         // f4 col within M (lanes contiguous)
        const int p = t / MCOLS;         // run of 11 output rows: p*11 + i
        const int colf4 = w0 * 2 - 8 + c;
        const bool colok = (colf4 >= 0) & (colf4 < W_F4);

        float4 v[20];
#pragma unroll
        for (int q = 0; q < 20; q++) {   // input rows h0 + p*11 - 4 + q
            int h = h0 + p * 11 - 4 + q;
            bool ok = colok & (h >= 0) & (h < 512);
            v[q] = ok ? img[(size_t)h * W_F4 + colf4] : ident4;
        }
        run11<IS_MIN>(v, [&](int i, float4 val) {
            int o = p * 11 + i;          // output row within tile
            if (o < TH) sM[o * S_M + c] = val;
        });
    }
    __syncthreads();

    // ---- phase 2: W-op, sM -> global.  192 tasks: c4, r, p(run of 11 px) ----
    if (t < 192) {
        const int c4 = t & 1;
        const int r  = (t >> 1) & 31;
        const int p  = t >> 6;           // 0..2

        float4 v[20];
#pragma unroll
        for (int q = 0; q < 20; q++) {   // M col m = p*11 + q (px units)
            int m = p * 11 + q;
            v[q] = (m < TW + 9) ? sM[r * S_M + m * 2 + c4] : ident4;
        }
        const size_t rowbase = (size_t)(h0 + r) * W_F4 + (size_t)w0 * 2 + c4;
        run11<IS_MIN>(v, [&](int i, float4 val) {
            int o = p * 11 + i;          // output px within tile
            if (o < TW) oimg[rowbase + o * 2] = val;
        });
    }
}

extern "C" void kernel_launch(void* const* d_in, const int* in_sizes, int n_in,
                              void* d_out, int out_size, void* d_ws, size_t ws_size,
                              hipStream_t stream) {
    const float4* in  = (const float4*)d_in[0];
    float4*       out = (float4*)d_out;
    float4*       ws  = (float4*)d_ws;   // eroded intermediate (128 MiB)

    dim3 grid(512 / TW, 512 / TH, 16);   // 16 x 16 x 16 = 4096 blocks

    morph<true ><<<grid, 256, 0, stream>>>(in, ws);   // erosion
    morph<false><<<grid, 256, 0, stream>>>(ws, out);  // dilation
}